// Round 2
// baseline (7445.527 us; speedup 1.0000x reference)
//
#include <hip/hip_runtime.h>

#define BB 256
#define LL 128
#define HH 512
#define H4 2048

typedef unsigned short us;
typedef __attribute__((ext_vector_type(8))) __bf16 bf16x8;
typedef __attribute__((ext_vector_type(4))) float f32x4;

__device__ __forceinline__ float bf2f(us s) {
    unsigned u = ((unsigned)s) << 16;
    return __builtin_bit_cast(float, u);
}
__device__ __forceinline__ us f2bf(float f) {
    unsigned u = __builtin_bit_cast(unsigned, f);
    return (us)((u + 0x7fffu + ((u >> 16) & 1u)) >> 16);
}
__device__ __forceinline__ float sigm(float x) { return 1.f / (1.f + __expf(-x)); }
__device__ __forceinline__ float tanh_(float x) { return 1.f - 2.f / (1.f + __expf(2.f * x)); }

__device__ __forceinline__ bf16x8 ldb8(const us* p) {
    return *(const bf16x8*)(const void*)p;
}

// ---------------- f32 -> bf16 bulk convert (n multiple of 256) ----------------
__global__ __launch_bounds__(256) void k_f2b(const float* __restrict__ src, us* __restrict__ dst) {
    int i = blockIdx.x * 256 + threadIdx.x;
    dst[i] = f2bf(src[i]);
}

// ---------------- repack dec_Wi f32 [2048,513] -> bf16 [2048,512] + last col f32 ----------------
__global__ __launch_bounds__(256) void k_repack(const float* __restrict__ Wi,
                                                us* __restrict__ wiR,
                                                float* __restrict__ wi_last) {
    int r = blockIdx.x;
    int tid = threadIdx.x;
    const float* src = Wi + (size_t)r * 513;
    wiR[(size_t)r * HH + tid] = f2bf(src[tid]);
    wiR[(size_t)r * HH + tid + 256] = f2bf(src[tid + 256]);
    if (tid == 0) wi_last[r] = src[512];
}

// ---------------- encoder step: z = x*Wi + h_{t-1}@Wh^T + b ; LSTM gates ----------------
// grid (16 batch-tiles, 32 col-groups), block 64 (1 wave).
// D layout (verified): m = quad*4+reg (batch), n = lane&15 (col). A: [m=lane&15][k=quad*8+j].
__global__ __launch_bounds__(64) void k_enc(const us* __restrict__ Wh, const float* __restrict__ Wi,
                                            const float* __restrict__ bvec, const int* __restrict__ xs,
                                            us* __restrict__ enc_out, float* __restrict__ c_ws,
                                            us* __restrict__ h_dec, int t) {
    int lane = threadIdx.x;
    int l15 = lane & 15, quad = lane >> 4;
    int b0 = blockIdx.x * 16;
    int c0 = blockIdx.y * 16;
    f32x4 acc[4] = {};
    if (t > 0) {
        const us* Arow = enc_out + ((size_t)(b0 + l15) * LL + (t - 1)) * HH + quad * 8;
        const us* Brow = Wh + (size_t)(c0 + l15) * HH + quad * 8;
#pragma unroll 4
        for (int kk = 0; kk < 16; ++kk) {
            bf16x8 a = ldb8(Arow + kk * 32);
#pragma unroll
            for (int g = 0; g < 4; ++g) {
                bf16x8 b = ldb8(Brow + (size_t)g * HH * HH + kk * 32);
                acc[g] = __builtin_amdgcn_mfma_f32_16x16x32_bf16(a, b, acc[g], 0, 0, 0);
            }
        }
    }
    int col = c0 + l15;
    float bi[4], wi[4];
#pragma unroll
    for (int g = 0; g < 4; ++g) {
        int rg = g * HH + col;
        bi[g] = bvec[rg];
        wi[g] = Wi[rg];
    }
#pragma unroll
    for (int r = 0; r < 4; ++r) {
        int b = b0 + quad * 4 + r;
        float xv = (float)xs[b * LL + t];
        float zi = acc[0][r] + bi[0] + xv * wi[0];
        float zf = acc[1][r] + bi[1] + xv * wi[1];
        float zg = acc[2][r] + bi[2] + xv * wi[2];
        float zo = acc[3][r] + bi[3] + xv * wi[3];
        float* cp = c_ws + (size_t)b * HH + col;
        float c_ = sigm(zf) * cp[0] + sigm(zi) * tanh_(zg);
        cp[0] = c_;
        us hb = f2bf(sigm(zo) * tanh_(c_));
        enc_out[((size_t)b * LL + t) * HH + col] = hb;
        if (t == LL - 1) h_dec[(size_t)b * HH + col] = hb;
    }
}

// ---------------- generic D[M,512]bf16 = A[M,512] @ Bt[512,512]^T (all bf16) ----------------
// grid (M/16, 8), block 64. Wave: 16 m x 64 n (4 tiles).
__global__ __launch_bounds__(64) void k_gemm_bt(const us* __restrict__ A, const us* __restrict__ Bt,
                                                us* __restrict__ D) {
    int lane = threadIdx.x;
    int l15 = lane & 15, quad = lane >> 4;
    int m0 = blockIdx.x * 16;
    int n0 = blockIdx.y * 64;
    f32x4 acc[4] = {};
    const us* Ar = A + (size_t)(m0 + l15) * HH + quad * 8;
    const us* Br = Bt + (size_t)(n0 + l15) * HH + quad * 8;
#pragma unroll 4
    for (int kk = 0; kk < 16; ++kk) {
        bf16x8 a = ldb8(Ar + kk * 32);
#pragma unroll
        for (int tt = 0; tt < 4; ++tt) {
            bf16x8 b = ldb8(Br + (size_t)tt * 16 * HH + kk * 32);
            acc[tt] = __builtin_amdgcn_mfma_f32_16x16x32_bf16(a, b, acc[tt], 0, 0, 0);
        }
    }
#pragma unroll
    for (int tt = 0; tt < 4; ++tt)
#pragma unroll
        for (int r = 0; r < 4; ++r)
            D[(size_t)(m0 + quad * 4 + r) * HH + n0 + tt * 16 + l15] = f2bf(acc[tt][r]);
}

// ---------------- attention: scores, log_softmax (f32 out), context, teacher forcing ----------------
// grid 256 (1 block / batch), block 256.
__global__ __launch_bounds__(256) void k_attn(const us* __restrict__ q, const float* __restrict__ vt,
                                              const us* __restrict__ enc_w1, const us* __restrict__ enc_out,
                                              const int* __restrict__ xs, const int* __restrict__ argsort,
                                              float* __restrict__ out, us* __restrict__ ctx,
                                              float* __restrict__ din_next, int t) {
    __shared__ float qs[HH];
    __shared__ float vts[HH];
    __shared__ float part[256];
    __shared__ float aj[LL];
    __shared__ float redm[4];
    __shared__ float reds[4];
    int tid = threadIdx.x;
    int b = blockIdx.x;
    qs[tid] = bf2f(q[(size_t)b * HH + tid]);
    qs[tid + 256] = bf2f(q[(size_t)b * HH + tid + 256]);
    vts[tid] = vt[tid];
    vts[tid + 256] = vt[tid + 256];
    __syncthreads();

    int l = tid >> 1, half = tid & 1;
    const us* wp = enc_w1 + ((size_t)b * LL + l) * HH + half * 256;
    float s = 0.f;
#pragma unroll 4
    for (int k = 0; k < 256; ++k) {
        float x = bf2f(wp[k]) + qs[half * 256 + k];
        s += tanh_(x) * vts[half * 256 + k];
    }
    part[tid] = s;
    __syncthreads();

    bool act = tid < 128;
    float sc = 0.f;
    if (act) sc = part[2 * tid] + part[2 * tid + 1];
    float m = act ? sc : -1e30f;
#pragma unroll
    for (int off = 1; off < 64; off <<= 1) m = fmaxf(m, __shfl_xor(m, off));
    if ((tid & 63) == 0) redm[tid >> 6] = m;
    __syncthreads();
    float M = fmaxf(fmaxf(redm[0], redm[1]), fmaxf(redm[2], redm[3]));
    float e = act ? __expf(sc - M) : 0.f;
    float ss = e;
#pragma unroll
    for (int off = 1; off < 64; off <<= 1) ss += __shfl_xor(ss, off);
    if ((tid & 63) == 0) reds[tid >> 6] = ss;
    __syncthreads();
    float S = reds[0] + reds[1] + reds[2] + reds[3];
    if (act) {
        out[((size_t)b * LL + t) * LL + tid] = sc - M - __logf(S);
        aj[tid] = e / S;
    }
    __syncthreads();

    // context[h] = sum_l aj[l] * enc_out[b][l][h]; thread handles h = 2*tid, 2*tid+1
    const us* ep = enc_out + (size_t)b * LL * HH + 2 * tid;
    float c0 = 0.f, c1 = 0.f;
#pragma unroll 8
    for (int l2 = 0; l2 < LL; ++l2) {
        unsigned u = *(const unsigned*)(const void*)(ep + (size_t)l2 * HH);
        float w = aj[l2];
        c0 += w * bf2f((us)(u & 0xffffu));
        c1 += w * bf2f((us)(u >> 16));
    }
    unsigned packed = (unsigned)f2bf(c0) | ((unsigned)f2bf(c1) << 16);
    *(unsigned*)(void*)(ctx + (size_t)b * HH + 2 * tid) = packed;

    if (tid == 0) {
        int idx = argsort[b * LL + t];
        din_next[b] = (float)xs[b * LL + idx];
    }
}

// ---------------- decoder LSTM step: z = [ctx,din]@Wi^T + h@Wh^T + b ; gates ----------------
// grid (16, 32), block 64. Same tiling as k_enc, two K=512 passes.
__global__ __launch_bounds__(64) void k_zdec(const us* __restrict__ ctx, const us* __restrict__ hcur,
                                             const us* __restrict__ wiR, const float* __restrict__ wi_last,
                                             const us* __restrict__ Wh, const float* __restrict__ bvec,
                                             const float* __restrict__ din, float* __restrict__ c_ws,
                                             us* __restrict__ hnext) {
    int lane = threadIdx.x;
    int l15 = lane & 15, quad = lane >> 4;
    int b0 = blockIdx.x * 16;
    int c0 = blockIdx.y * 16;
    f32x4 acc[4] = {};
    const us* A1 = ctx + (size_t)(b0 + l15) * HH + quad * 8;
    const us* B1 = wiR + (size_t)(c0 + l15) * HH + quad * 8;
#pragma unroll 4
    for (int kk = 0; kk < 16; ++kk) {
        bf16x8 a = ldb8(A1 + kk * 32);
#pragma unroll
        for (int g = 0; g < 4; ++g) {
            bf16x8 b = ldb8(B1 + (size_t)g * HH * HH + kk * 32);
            acc[g] = __builtin_amdgcn_mfma_f32_16x16x32_bf16(a, b, acc[g], 0, 0, 0);
        }
    }
    const us* A2 = hcur + (size_t)(b0 + l15) * HH + quad * 8;
    const us* B2 = Wh + (size_t)(c0 + l15) * HH + quad * 8;
#pragma unroll 4
    for (int kk = 0; kk < 16; ++kk) {
        bf16x8 a = ldb8(A2 + kk * 32);
#pragma unroll
        for (int g = 0; g < 4; ++g) {
            bf16x8 b = ldb8(B2 + (size_t)g * HH * HH + kk * 32);
            acc[g] = __builtin_amdgcn_mfma_f32_16x16x32_bf16(a, b, acc[g], 0, 0, 0);
        }
    }
    int col = c0 + l15;
    float bi[4], wl[4];
#pragma unroll
    for (int g = 0; g < 4; ++g) {
        int rg = g * HH + col;
        bi[g] = bvec[rg];
        wl[g] = wi_last[rg];
    }
#pragma unroll
    for (int r = 0; r < 4; ++r) {
        int b = b0 + quad * 4 + r;
        float dv = din[b];
        float zi = acc[0][r] + bi[0] + dv * wl[0];
        float zf = acc[1][r] + bi[1] + dv * wl[1];
        float zg = acc[2][r] + bi[2] + dv * wl[2];
        float zo = acc[3][r] + bi[3] + dv * wl[3];
        float* cp = c_ws + (size_t)b * HH + col;
        float c_ = sigm(zf) * cp[0] + sigm(zi) * tanh_(zg);
        cp[0] = c_;
        hnext[(size_t)b * HH + col] = f2bf(sigm(zo) * tanh_(c_));
    }
}

extern "C" void kernel_launch(void* const* d_in, const int* in_sizes, int n_in,
                              void* d_out, int out_size, void* d_ws, size_t ws_size,
                              hipStream_t stream) {
    const int* xs = (const int*)d_in[0];
    const int* argsort = (const int*)d_in[2];
    const float* enc_Wi = (const float*)d_in[3];
    const float* enc_Wh = (const float*)d_in[4];
    const float* enc_b = (const float*)d_in[5];
    const float* dec_Wi = (const float*)d_in[6];
    const float* dec_Wh = (const float*)d_in[7];
    const float* dec_b = (const float*)d_in[8];
    const float* w1 = (const float*)d_in[9];
    const float* w2 = (const float*)d_in[10];
    const float* vt = (const float*)d_in[11];
    float* out = (float*)d_out;

    // workspace layout (all 16B-aligned)
    char* ws = (char*)d_ws;
    float* c_ws = (float*)(ws);                 // 256*512*4      = 524288
    float* din = (float*)(ws + 524288);         // 2*256*4        = 2048
    us* hdec = (us*)(ws + 526336);              // 2*256*512*2    = 524288
    us* q = (us*)(ws + 1050624);                // 256*512*2      = 262144
    us* ctx = (us*)(ws + 1312768);              // 256*512*2      = 262144
    us* wiR = (us*)(ws + 1574912);              // 2048*512*2     = 2097152
    float* wi_last = (float*)(ws + 3672064);    // 2048*4         = 8192
    us* whE = (us*)(ws + 3680256);              // 2048*512*2     = 2097152
    us* whD = (us*)(ws + 5777408);              // 2048*512*2     = 2097152
    us* w1B = (us*)(ws + 7874560);              // 512*512*2      = 524288
    us* w2B = (us*)(ws + 8398848);              // 512*512*2      = 524288
    us* enc_out = (us*)(ws + 8923136);          // 256*128*512*2  = 33554432
    us* enc_w1 = (us*)(ws + 42477568);          // 33554432 -> end 76032000

    // zero c-state and both dec_in slots (contiguous region)
    hipMemsetAsync(ws, 0, 526336, stream);

    // weight conversions (f32 -> bf16 ws copies), every launch (ws is re-poisoned)
    k_f2b<<<H4 * HH / 256, 256, 0, stream>>>(enc_Wh, whE);
    k_f2b<<<H4 * HH / 256, 256, 0, stream>>>(dec_Wh, whD);
    k_f2b<<<HH * HH / 256, 256, 0, stream>>>(w1, w1B);
    k_f2b<<<HH * HH / 256, 256, 0, stream>>>(w2, w2B);
    k_repack<<<H4, 256, 0, stream>>>(dec_Wi, wiR, wi_last);

    // encoder
    for (int t = 0; t < LL; ++t)
        k_enc<<<dim3(16, 32), 64, 0, stream>>>(whE, enc_Wi, enc_b, xs, enc_out, c_ws,
                                               hdec /*slot 0*/, t);

    // enc_w1 = enc_out @ w1^T  (M = B*L = 32768)
    k_gemm_bt<<<dim3(2048, 8), 64, 0, stream>>>(enc_out, w1B, enc_w1);

    // decoder
    for (int t = 0; t < LL; ++t) {
        us* hcur = hdec + (size_t)(t & 1) * BB * HH;
        us* hnxt = hdec + (size_t)((t + 1) & 1) * BB * HH;
        float* dcur = din + (size_t)(t & 1) * BB;
        float* dnxt = din + (size_t)((t + 1) & 1) * BB;
        k_gemm_bt<<<dim3(16, 8), 64, 0, stream>>>(hcur, w2B, q);
        k_attn<<<256, 256, 0, stream>>>(q, vt, enc_w1, enc_out, xs, argsort, out, ctx, dnxt, t);
        k_zdec<<<dim3(16, 32), 64, 0, stream>>>(ctx, hcur, wiR, wi_last, whD, dec_b, dcur,
                                                c_ws, hnxt);
    }
    (void)in_sizes; (void)n_in; (void)out_size; (void)ws_size;
}

// Round 3
// 6728.207 us; speedup vs baseline: 1.1066x; 1.1066x over previous
//
#include <hip/hip_runtime.h>

#define BB 256
#define LL 128
#define HH 512
#define H4 2048

typedef unsigned short us;
typedef __attribute__((ext_vector_type(8))) __bf16 bf16x8;
typedef __attribute__((ext_vector_type(4))) float f32x4;

__device__ __forceinline__ float bf2f(us s) {
    unsigned u = ((unsigned)s) << 16;
    return __builtin_bit_cast(float, u);
}
__device__ __forceinline__ us f2bf(float f) {
    unsigned u = __builtin_bit_cast(unsigned, f);
    return (us)((u + 0x7fffu + ((u >> 16) & 1u)) >> 16);
}
__device__ __forceinline__ float sigm(float x) { return 1.f / (1.f + __expf(-x)); }
__device__ __forceinline__ float tanh_(float x) { return 1.f - 2.f / (1.f + __expf(2.f * x)); }

__device__ __forceinline__ bf16x8 ldb8(const us* p) {
    return *(const bf16x8*)(const void*)p;
}

// ---------------- f32 -> bf16 bulk convert (n multiple of 256) ----------------
__global__ __launch_bounds__(256) void k_f2b(const float* __restrict__ src, us* __restrict__ dst) {
    int i = blockIdx.x * 256 + threadIdx.x;
    dst[i] = f2bf(src[i]);
}

// ---------------- repack dec_Wi f32 [2048,513] -> bf16 [2048,512] + last col f32 ----------------
__global__ __launch_bounds__(256) void k_repack(const float* __restrict__ Wi,
                                                us* __restrict__ wiR,
                                                float* __restrict__ wi_last) {
    int r = blockIdx.x;
    int tid = threadIdx.x;
    const float* src = Wi + (size_t)r * 513;
    wiR[(size_t)r * HH + tid] = f2bf(src[tid]);
    wiR[(size_t)r * HH + tid + 256] = f2bf(src[tid + 256]);
    if (tid == 0) wi_last[r] = src[512];
}

// ---------------- encoder step: z = x*Wi + h_{t-1}@Wh^T + b ; LSTM gates ----------------
// grid (16 batch-tiles, 32 col-groups), block 64 (1 wave).
// D layout (verified): m = quad*4+reg (batch), n = lane&15 (col). A: [m=lane&15][k=quad*8+j].
__global__ __launch_bounds__(64) void k_enc(const us* __restrict__ Wh, const float* __restrict__ Wi,
                                            const float* __restrict__ bvec, const int* __restrict__ xs,
                                            us* __restrict__ enc_out, float* __restrict__ c_ws,
                                            us* __restrict__ h_dec, int t) {
    int lane = threadIdx.x;
    int l15 = lane & 15, quad = lane >> 4;
    int b0 = blockIdx.x * 16;
    int c0 = blockIdx.y * 16;
    f32x4 acc[4] = {};
    if (t > 0) {
        const us* Arow = enc_out + ((size_t)(b0 + l15) * LL + (t - 1)) * HH + quad * 8;
        const us* Brow = Wh + (size_t)(c0 + l15) * HH + quad * 8;
#pragma unroll 4
        for (int kk = 0; kk < 16; ++kk) {
            bf16x8 a = ldb8(Arow + kk * 32);
#pragma unroll
            for (int g = 0; g < 4; ++g) {
                bf16x8 b = ldb8(Brow + (size_t)g * HH * HH + kk * 32);
                acc[g] = __builtin_amdgcn_mfma_f32_16x16x32_bf16(a, b, acc[g], 0, 0, 0);
            }
        }
    }
    int col = c0 + l15;
    float bi[4], wi[4];
#pragma unroll
    for (int g = 0; g < 4; ++g) {
        int rg = g * HH + col;
        bi[g] = bvec[rg];
        wi[g] = Wi[rg];
    }
#pragma unroll
    for (int r = 0; r < 4; ++r) {
        int b = b0 + quad * 4 + r;
        float xv = (float)xs[b * LL + t];
        float zi = acc[0][r] + bi[0] + xv * wi[0];
        float zf = acc[1][r] + bi[1] + xv * wi[1];
        float zg = acc[2][r] + bi[2] + xv * wi[2];
        float zo = acc[3][r] + bi[3] + xv * wi[3];
        float* cp = c_ws + (size_t)b * HH + col;
        float c_ = sigm(zf) * cp[0] + sigm(zi) * tanh_(zg);
        cp[0] = c_;
        us hb = f2bf(sigm(zo) * tanh_(c_));
        enc_out[((size_t)b * LL + t) * HH + col] = hb;
        if (t == LL - 1) h_dec[(size_t)b * HH + col] = hb;
    }
}

// ---------------- generic D[M,512]bf16 = A[M,512] @ Bt[512,512]^T (all bf16) ----------------
// grid (M/16, 8), block 64. Wave: 16 m x 64 n (4 tiles).
__global__ __launch_bounds__(64) void k_gemm_bt(const us* __restrict__ A, const us* __restrict__ Bt,
                                                us* __restrict__ D) {
    int lane = threadIdx.x;
    int l15 = lane & 15, quad = lane >> 4;
    int m0 = blockIdx.x * 16;
    int n0 = blockIdx.y * 64;
    f32x4 acc[4] = {};
    const us* Ar = A + (size_t)(m0 + l15) * HH + quad * 8;
    const us* Br = Bt + (size_t)(n0 + l15) * HH + quad * 8;
#pragma unroll 4
    for (int kk = 0; kk < 16; ++kk) {
        bf16x8 a = ldb8(Ar + kk * 32);
#pragma unroll
        for (int tt = 0; tt < 4; ++tt) {
            bf16x8 b = ldb8(Br + (size_t)tt * 16 * HH + kk * 32);
            acc[tt] = __builtin_amdgcn_mfma_f32_16x16x32_bf16(a, b, acc[tt], 0, 0, 0);
        }
    }
#pragma unroll
    for (int tt = 0; tt < 4; ++tt)
#pragma unroll
        for (int r = 0; r < 4; ++r)
            D[(size_t)(m0 + quad * 4 + r) * HH + n0 + tt * 16 + l15] = f2bf(acc[tt][r]);
}

// ---------------- attention: scores, log_softmax (f32 out), context, teacher forcing ----------------
// grid 256 (1 block / batch), block 512 (8 waves).
// Score phase: lane owns k = lane*8..lane*8+7 (q, vt cached in regs); per row one coalesced
// bf16x8 load of enc_w1 + butterfly reduce. Wave w handles rows l = i*8 + w.
__global__ __launch_bounds__(512) void k_attn(const us* __restrict__ q, const float* __restrict__ vt,
                                              const us* __restrict__ enc_w1, const us* __restrict__ enc_out,
                                              const int* __restrict__ xs, const int* __restrict__ argsort,
                                              float* __restrict__ out, us* __restrict__ ctx,
                                              float* __restrict__ din_next, int t) {
    __shared__ float scs[LL];
    __shared__ float aj[LL];
    __shared__ float redm[2];
    __shared__ float reds[2];
    int tid = threadIdx.x;
    int b = blockIdx.x;
    int lane = tid & 63;
    int w = tid >> 6;

    // per-lane constants: q[b][k0..k0+7] (bf16) and vt[k0..k0+7] (f32)
    int k0 = lane * 8;
    bf16x8 qv = ldb8(q + (size_t)b * HH + k0);
    float qk[8], vtk[8];
#pragma unroll
    for (int j = 0; j < 8; ++j) {
        qk[j] = (float)qv[j];
        vtk[j] = vt[k0 + j];
    }

    // scores: wave w computes rows l = i*8 + w
    const us* wbase = enc_w1 + (size_t)b * LL * HH + k0;
#pragma unroll 4
    for (int i = 0; i < 16; ++i) {
        int l = i * 8 + w;
        bf16x8 e8 = ldb8(wbase + (size_t)l * HH);
        float s = 0.f;
#pragma unroll
        for (int j = 0; j < 8; ++j) s += tanh_((float)e8[j] + qk[j]) * vtk[j];
#pragma unroll
        for (int off = 1; off < 64; off <<= 1) s += __shfl_xor(s, off);
        if (lane == 0) scs[l] = s;
    }
    __syncthreads();

    // softmax over 128 (threads 0..127 active)
    bool act = tid < 128;
    float sc = act ? scs[tid] : -1e30f;
    float m = sc;
#pragma unroll
    for (int off = 1; off < 64; off <<= 1) m = fmaxf(m, __shfl_xor(m, off));
    if (act && lane == 0) redm[w] = m;
    __syncthreads();
    float M = fmaxf(redm[0], redm[1]);
    float e = act ? __expf(sc - M) : 0.f;
    float ss = e;
#pragma unroll
    for (int off = 1; off < 64; off <<= 1) ss += __shfl_xor(ss, off);
    if (act && lane == 0) reds[w] = ss;
    __syncthreads();
    float S = reds[0] + reds[1];
    if (act) {
        out[((size_t)b * LL + t) * LL + tid] = sc - M - __logf(S);
        aj[tid] = e / S;
    }
    __syncthreads();

    // context[h] = sum_l aj[l] * enc_out[b][l][h]; thread owns h = tid (coalesced 2B/lane)
    const us* ep = enc_out + (size_t)b * LL * HH + tid;
    float c0 = 0.f;
#pragma unroll 8
    for (int l2 = 0; l2 < LL; ++l2)
        c0 += aj[l2] * bf2f(ep[(size_t)l2 * HH]);
    ctx[(size_t)b * HH + tid] = f2bf(c0);

    if (tid == 0) {
        int idx = argsort[b * LL + t];
        din_next[b] = (float)xs[b * LL + idx];
    }
}

// ---------------- decoder LSTM step: z = [ctx,din]@Wi^T + h@Wh^T + b ; gates ----------------
// grid (16, 32), block 64. Same tiling as k_enc, two K=512 passes.
__global__ __launch_bounds__(64) void k_zdec(const us* __restrict__ ctx, const us* __restrict__ hcur,
                                             const us* __restrict__ wiR, const float* __restrict__ wi_last,
                                             const us* __restrict__ Wh, const float* __restrict__ bvec,
                                             const float* __restrict__ din, float* __restrict__ c_ws,
                                             us* __restrict__ hnext) {
    int lane = threadIdx.x;
    int l15 = lane & 15, quad = lane >> 4;
    int b0 = blockIdx.x * 16;
    int c0 = blockIdx.y * 16;
    f32x4 acc[4] = {};
    const us* A1 = ctx + (size_t)(b0 + l15) * HH + quad * 8;
    const us* B1 = wiR + (size_t)(c0 + l15) * HH + quad * 8;
#pragma unroll 4
    for (int kk = 0; kk < 16; ++kk) {
        bf16x8 a = ldb8(A1 + kk * 32);
#pragma unroll
        for (int g = 0; g < 4; ++g) {
            bf16x8 b = ldb8(B1 + (size_t)g * HH * HH + kk * 32);
            acc[g] = __builtin_amdgcn_mfma_f32_16x16x32_bf16(a, b, acc[g], 0, 0, 0);
        }
    }
    const us* A2 = hcur + (size_t)(b0 + l15) * HH + quad * 8;
    const us* B2 = Wh + (size_t)(c0 + l15) * HH + quad * 8;
#pragma unroll 4
    for (int kk = 0; kk < 16; ++kk) {
        bf16x8 a = ldb8(A2 + kk * 32);
#pragma unroll
        for (int g = 0; g < 4; ++g) {
            bf16x8 b = ldb8(B2 + (size_t)g * HH * HH + kk * 32);
            acc[g] = __builtin_amdgcn_mfma_f32_16x16x32_bf16(a, b, acc[g], 0, 0, 0);
        }
    }
    int col = c0 + l15;
    float bi[4], wl[4];
#pragma unroll
    for (int g = 0; g < 4; ++g) {
        int rg = g * HH + col;
        bi[g] = bvec[rg];
        wl[g] = wi_last[rg];
    }
#pragma unroll
    for (int r = 0; r < 4; ++r) {
        int b = b0 + quad * 4 + r;
        float dv = din[b];
        float zi = acc[0][r] + bi[0] + dv * wl[0];
        float zf = acc[1][r] + bi[1] + dv * wl[1];
        float zg = acc[2][r] + bi[2] + dv * wl[2];
        float zo = acc[3][r] + bi[3] + dv * wl[3];
        float* cp = c_ws + (size_t)b * HH + col;
        float c_ = sigm(zf) * cp[0] + sigm(zi) * tanh_(zg);
        cp[0] = c_;
        hnext[(size_t)b * HH + col] = f2bf(sigm(zo) * tanh_(c_));
    }
}

extern "C" void kernel_launch(void* const* d_in, const int* in_sizes, int n_in,
                              void* d_out, int out_size, void* d_ws, size_t ws_size,
                              hipStream_t stream) {
    const int* xs = (const int*)d_in[0];
    const int* argsort = (const int*)d_in[2];
    const float* enc_Wi = (const float*)d_in[3];
    const float* enc_Wh = (const float*)d_in[4];
    const float* enc_b = (const float*)d_in[5];
    const float* dec_Wi = (const float*)d_in[6];
    const float* dec_Wh = (const float*)d_in[7];
    const float* dec_b = (const float*)d_in[8];
    const float* w1 = (const float*)d_in[9];
    const float* w2 = (const float*)d_in[10];
    const float* vt = (const float*)d_in[11];
    float* out = (float*)d_out;

    // workspace layout (all 16B-aligned)
    char* ws = (char*)d_ws;
    float* c_ws = (float*)(ws);                 // 256*512*4      = 524288
    float* din = (float*)(ws + 524288);         // 2*256*4        = 2048
    us* hdec = (us*)(ws + 526336);              // 2*256*512*2    = 524288
    us* q = (us*)(ws + 1050624);                // 256*512*2      = 262144
    us* ctx = (us*)(ws + 1312768);              // 256*512*2      = 262144
    us* wiR = (us*)(ws + 1574912);              // 2048*512*2     = 2097152
    float* wi_last = (float*)(ws + 3672064);    // 2048*4         = 8192
    us* whE = (us*)(ws + 3680256);              // 2048*512*2     = 2097152
    us* whD = (us*)(ws + 5777408);              // 2048*512*2     = 2097152
    us* w1B = (us*)(ws + 7874560);              // 512*512*2      = 524288
    us* w2B = (us*)(ws + 8398848);              // 512*512*2      = 524288
    us* enc_out = (us*)(ws + 8923136);          // 256*128*512*2  = 33554432
    us* enc_w1 = (us*)(ws + 42477568);          // 33554432 -> end 76032000

    // zero c-state and both dec_in slots (contiguous region)
    hipMemsetAsync(ws, 0, 526336, stream);

    // weight conversions (f32 -> bf16 ws copies), every launch (ws is re-poisoned)
    k_f2b<<<H4 * HH / 256, 256, 0, stream>>>(enc_Wh, whE);
    k_f2b<<<H4 * HH / 256, 256, 0, stream>>>(dec_Wh, whD);
    k_f2b<<<HH * HH / 256, 256, 0, stream>>>(w1, w1B);
    k_f2b<<<HH * HH / 256, 256, 0, stream>>>(w2, w2B);
    k_repack<<<H4, 256, 0, stream>>>(dec_Wi, wiR, wi_last);

    // encoder
    for (int t = 0; t < LL; ++t)
        k_enc<<<dim3(16, 32), 64, 0, stream>>>(whE, enc_Wi, enc_b, xs, enc_out, c_ws,
                                               hdec /*slot 0*/, t);

    // enc_w1 = enc_out @ w1^T  (M = B*L = 32768)
    k_gemm_bt<<<dim3(2048, 8), 64, 0, stream>>>(enc_out, w1B, enc_w1);

    // decoder
    for (int t = 0; t < LL; ++t) {
        us* hcur = hdec + (size_t)(t & 1) * BB * HH;
        us* hnxt = hdec + (size_t)((t + 1) & 1) * BB * HH;
        float* dcur = din + (size_t)(t & 1) * BB;
        float* dnxt = din + (size_t)((t + 1) & 1) * BB;
        k_gemm_bt<<<dim3(16, 8), 64, 0, stream>>>(hcur, w2B, q);
        k_attn<<<256, 512, 0, stream>>>(q, vt, enc_w1, enc_out, xs, argsort, out, ctx, dnxt, t);
        k_zdec<<<dim3(16, 32), 64, 0, stream>>>(ctx, hcur, wiR, wi_last, whD, dec_b, dcur,
                                                c_ws, hnxt);
    }
    (void)in_sizes; (void)n_in; (void)out_size; (void)ws_size;
}